// Round 3
// baseline (872.786 us; speedup 1.0000x reference)
//
#include <hip/hip_runtime.h>
#include <hip/hip_bf16.h>
#include <stdint.h>

#define DIM 128
#define BSTRIDE 136  // padded row stride (bf16 elems) for WkT in LDS: 272 B -> uniform 8-way (minimal) bank pattern for ds_read_b128

typedef float v4f __attribute__((ext_vector_type(4)));
typedef short v8s __attribute__((ext_vector_type(8)));

__device__ __forceinline__ unsigned short f2bf(float f) {
    union { float f; unsigned u; } c; c.f = f;
    unsigned r = c.u + 0x7fffu + ((c.u >> 16) & 1u);
    return (unsigned short)(r >> 16);
}

// ---------------- K0 (merged setup): qry GEMV + WkT transpose + accumulator zero ----------------
__global__ __launch_bounds__(256) void setup_kernel(const float* __restrict__ feat_u,
                                                    const float* __restrict__ W_user,
                                                    const float* __restrict__ b_user,
                                                    const float* __restrict__ W_key,
                                                    float* __restrict__ qry,
                                                    unsigned short* __restrict__ WkT,
                                                    float* __restrict__ numer,
                                                    float* __restrict__ denom,
                                                    int B) {
    __shared__ float fu[2][DIM];
    const int blk = blockIdx.x, t = threadIdx.x;
    const int qblocks = (B + 1) >> 1;
    if (blk < qblocks) {
        const int half = t >> 7, d = t & 127;
        const int b = blk * 2 + half;
        if (b < B) fu[half][d] = feat_u[b * DIM + d];
        __syncthreads();
        if (b < B) {
            float acc = b_user[d];
#pragma unroll 8
            for (int k = 0; k < DIM; ++k) acc += fu[half][k] * W_user[k * DIM + d];
            qry[b * DIM + d] = acc;
        }
    } else if (blk < qblocks + 64) {
        const int tid = (blk - qblocks) * 256 + t;
        const int k = tid >> 7, d = tid & 127;
        WkT[d * BSTRIDE + k] = f2bf(W_key[k * DIM + d]);
    } else {
        const int i = (blk - qblocks - 64) * 256 + t;
        if (i < B * DIM) numer[i] = 0.f;
        if (i < B) denom[i] = 0.f;
    }
}

// ---------------- K1 (fused, software-pipelined): per node ex = exp(sigmoid(qry+key)@W_e),
// accumulate numer[seg] += ex*feat_i, denom[seg] += ex (per-wave run, atomic flush on seg change).
// block = 256 threads (4 waves). Each wave: 8 strips of 16 nodes; strip s+1's A-loads are
// issued during strip s's body (MFMA+epilogue+phase2 ~1500cy hides global-load latency). ----------------
__global__ __launch_bounds__(256, 3) void fused_kernel(const float* __restrict__ feat_i,
                                                       const int* __restrict__ seg,
                                                       const unsigned short* __restrict__ WkT,
                                                       const float* __restrict__ qry,
                                                       const float* __restrict__ W_e,
                                                       float* __restrict__ numer,
                                                       float* __restrict__ denom,
                                                       int N) {
    __shared__ __align__(16) unsigned short Blds[DIM * BSTRIDE];  // 34816 B
    __shared__ float We[DIM];
    int t = threadIdx.x;

    // stage WkT -> LDS as float4 chunks (34816 B = 2176 x 16 B)
    {
        const float4* src = (const float4*)WkT;
        float4* dst = (float4*)Blds;
        for (int i = t; i < (DIM * BSTRIDE) / 8; i += 256) dst[i] = src[i];
    }
    if (t < DIM) We[t] = W_e[t];
    __syncthreads();

    const int wave = t >> 6, lane = t & 63;
    const int m = lane & 15, quad = lane >> 4;
    const int base = blockIdx.x * 512 + wave * 128;
    const float2* f2 = (const float2*)feat_i;

    // strip-invariant W_e fragment (col = c*16+m) in registers
    float we[8];
#pragma unroll
    for (int c = 0; c < 8; ++c) we[c] = We[c * 16 + m];

    // phase-2 running state (lane owns output columns 2*lane, 2*lane+1)
    float2 wacc; wacc.x = 0.f; wacc.y = 0.f;
    float dsum = 0.f;
    int cur_sg = -1;

#define FLUSH()                                                            \
    do {                                                                   \
        atomicAdd(&numer[cur_sg * DIM + 2 * lane], wacc.x);                \
        atomicAdd(&numer[cur_sg * DIM + 2 * lane + 1], wacc.y);            \
        if (lane == 0) atomicAdd(&denom[cur_sg], dsum);                    \
        wacc.x = 0.f; wacc.y = 0.f; dsum = 0.f;                            \
    } while (0)

    // ---- prefetch buffer: lane's A-row (16 nodes x 128 dims strip; lane holds row m, cols quad*8 + kc*32 ..) ----
    float4 pf[8];
    {
        const int n_a = base + m;
        const float* arow = feat_i + (size_t)(n_a < N ? n_a : 0) * DIM + quad * 8;
#pragma unroll
        for (int kc = 0; kc < 4; ++kc) {
            pf[2 * kc]     = *(const float4*)(arow + kc * 32);
            pf[2 * kc + 1] = *(const float4*)(arow + kc * 32 + 4);
        }
    }

#pragma unroll
    for (int s = 0; s < 8; ++s) {
        const int strip = base + s * 16;
        const bool va = (strip + m) < N;

        // ---- convert prefetched fp32 -> bf16 A fragments ----
        v8s a[4];
#pragma unroll
        for (int kc = 0; kc < 4; ++kc) {
            v8s af;
            af[0] = (short)f2bf(va ? pf[2 * kc].x : 0.f);
            af[1] = (short)f2bf(va ? pf[2 * kc].y : 0.f);
            af[2] = (short)f2bf(va ? pf[2 * kc].z : 0.f);
            af[3] = (short)f2bf(va ? pf[2 * kc].w : 0.f);
            af[4] = (short)f2bf(va ? pf[2 * kc + 1].x : 0.f);
            af[5] = (short)f2bf(va ? pf[2 * kc + 1].y : 0.f);
            af[6] = (short)f2bf(va ? pf[2 * kc + 1].z : 0.f);
            af[7] = (short)f2bf(va ? pf[2 * kc + 1].w : 0.f);
            a[kc] = af;
        }

        // ---- issue next strip's A-loads (in flight across this strip's body) ----
        if (s < 7) {
            const int n_n = base + (s + 1) * 16 + m;
            const float* arow = feat_i + (size_t)(n_n < N ? n_n : 0) * DIM + quad * 8;
#pragma unroll
            for (int kc = 0; kc < 4; ++kc) {
                pf[2 * kc]     = *(const float4*)(arow + kc * 32);
                pf[2 * kc + 1] = *(const float4*)(arow + kc * 32 + 4);
            }
        }

        // ---- MFMA: 8 col-tiles x 4 K-chunks ----
        v4f acc[8];
#pragma unroll
        for (int c = 0; c < 8; ++c) acc[c] = (v4f){0.f, 0.f, 0.f, 0.f};
#pragma unroll
        for (int c = 0; c < 8; ++c) {
            const unsigned short* brow = Blds + (c * 16 + m) * BSTRIDE + quad * 8;
#pragma unroll
            for (int kc = 0; kc < 4; ++kc) {
                v8s b = *(const v8s*)(brow + kc * 32);
                acc[c] = __builtin_amdgcn_mfma_f32_16x16x32_bf16(a[kc], b, acc[c], 0, 0, 0);
            }
        }

        // ---- epilogue: C row = quad*4 + r, col = c*16 + m ----
        float ev[4];
        int sgv[4];
#pragma unroll
        for (int r = 0; r < 4; ++r) {
            const int node = strip + quad * 4 + r;
            sgv[r] = (node < N) ? seg[node] : 0;
        }
        const int sgf = __shfl(sgv[0], 0);    // seg of first node in strip
        const int sgl = __shfl(sgv[3], 48);   // seg of last node in strip
        const bool uni = (sgf == sgl) && (strip + 15 < N);

        if (uni) {
            // strip-uniform segment: hoist qry gather (8 L2 loads instead of 32)
            float q[8];
#pragma unroll
            for (int c = 0; c < 8; ++c) q[c] = qry[sgf * DIM + c * 16 + m];
#pragma unroll
            for (int r = 0; r < 4; ++r) {
                float partial = 0.f;
#pragma unroll
                for (int c = 0; c < 8; ++c) {
                    const float x = acc[c][r] + q[c];
                    partial += __builtin_amdgcn_rcpf(1.0f + __expf(-x)) * we[c];
                }
                partial += __shfl_xor(partial, 1);
                partial += __shfl_xor(partial, 2);
                partial += __shfl_xor(partial, 4);
                partial += __shfl_xor(partial, 8);
                ev[r] = __expf(partial);
            }
        } else {
#pragma unroll
            for (int r = 0; r < 4; ++r) {
                const float* qrow = qry + sgv[r] * DIM;
                float partial = 0.f;
#pragma unroll
                for (int c = 0; c < 8; ++c) {
                    const float x = acc[c][r] + qrow[c * 16 + m];
                    partial += __builtin_amdgcn_rcpf(1.0f + __expf(-x)) * we[c];
                }
                partial += __shfl_xor(partial, 1);
                partial += __shfl_xor(partial, 2);
                partial += __shfl_xor(partial, 4);
                partial += __shfl_xor(partial, 8);
                ev[r] = __expf(partial);
            }
        }

        // ---- phase 2: ex-weighted accumulation over this strip's 16 nodes (L2-hot re-read) ----
        if (strip < N) {
            if (uni) {
                if (sgf != cur_sg) {
                    if (cur_sg >= 0) FLUSH();
                    cur_sg = sgf;
                }
#pragma unroll
                for (int i = 0; i < 16; ++i) {
                    const float w = __shfl(ev[i & 3], (i >> 2) * 16);
                    const float2 v = f2[(size_t)(strip + i) * 64 + lane];
                    wacc.x += w * v.x;
                    wacc.y += w * v.y;
                    dsum += w;
                }
            } else {
                // slow path: segment boundary (or N tail) inside the strip
#pragma unroll
                for (int i = 0; i < 16; ++i) {
                    const int n = strip + i;
                    if (n < N) {
                        const int sg = __shfl(sgv[i & 3], (i >> 2) * 16);
                        if (sg != cur_sg) {
                            if (cur_sg >= 0) FLUSH();
                            cur_sg = sg;
                        }
                        const float w = __shfl(ev[i & 3], (i >> 2) * 16);
                        const float2 v = f2[(size_t)n * 64 + lane];
                        wacc.x += w * v.x;
                        wacc.y += w * v.y;
                        dsum += w;
                    }
                }
            }
        }
    }

    if (cur_sg >= 0) FLUSH();
#undef FLUSH
}

// ---------------- K2: out[b][d] = numer[b][d] / denom[b] ----------------
__global__ void fin_kernel(const float* __restrict__ numer,
                           const float* __restrict__ denom,
                           float* __restrict__ out, int total) {
    int i = blockIdx.x * blockDim.x + threadIdx.x;
    if (i < total) {
        const float d = denom[i >> 7];
        out[i] = (d > 0.f) ? numer[i] / d : 0.f;
    }
}

extern "C" void kernel_launch(void* const* d_in, const int* in_sizes, int n_in,
                              void* d_out, int out_size, void* d_ws, size_t ws_size,
                              hipStream_t stream) {
    const float* feat_i = (const float*)d_in[0];
    const float* feat_u = (const float*)d_in[1];
    const int*   seg    = (const int*)d_in[2];
    const float* W_key  = (const float*)d_in[3];
    const float* W_user = (const float*)d_in[4];
    const float* b_user = (const float*)d_in[5];
    const float* W_e    = (const float*)d_in[6];
    float* out = (float*)d_out;

    const int N = in_sizes[2];
    const int B = in_sizes[1] / DIM;

    // workspace layout
    char* ws = (char*)d_ws;
    float*          qry   = (float*)ws;                                  // B*128*4   = 131072 B
    unsigned short* WkT   = (unsigned short*)(ws + 131072);              // 128*136*2 = 34816 B
    float*          numer = (float*)(ws + 131072 + 34816);               // B*128*4   = 131072 B
    float*          denom = (float*)(ws + 131072 + 34816 + 131072);     // B*4

    const int qblocks = (B + 1) >> 1;
    const int zblocks = (B * DIM + 255) / 256 + 1;
    setup_kernel<<<qblocks + 64 + zblocks, 256, 0, stream>>>(feat_u, W_user, b_user, W_key,
                                                             qry, WkT, numer, denom, B);

    const int nblk = (N + 511) / 512;
    fused_kernel<<<nblk, 256, 0, stream>>>(feat_i, seg, WkT, qry, W_e, numer, denom, N);

    fin_kernel<<<(B * DIM + 255) / 256, 256, 0, stream>>>(numer, denom, out, B * DIM);
}

// Round 4
// 792.780 us; speedup vs baseline: 1.1009x; 1.1009x over previous
//
#include <hip/hip_runtime.h>
#include <hip/hip_bf16.h>
#include <stdint.h>

#define DIM 128
#define BSTRIDE 136  // padded row stride (bf16 elems) for WkT in LDS: 272 B -> uniform 8-way (minimal) bank pattern for ds_read_b128

typedef float v4f __attribute__((ext_vector_type(4)));
typedef short v8s __attribute__((ext_vector_type(8)));

__device__ __forceinline__ unsigned short f2bf(float f) {
    union { float f; unsigned u; } c; c.f = f;
    unsigned r = c.u + 0x7fffu + ((c.u >> 16) & 1u);
    return (unsigned short)(r >> 16);
}

// ---------------- K0 (merged setup): qry GEMV + WkT transpose + accumulator zero ----------------
__global__ __launch_bounds__(256) void setup_kernel(const float* __restrict__ feat_u,
                                                    const float* __restrict__ W_user,
                                                    const float* __restrict__ b_user,
                                                    const float* __restrict__ W_key,
                                                    float* __restrict__ qry,
                                                    unsigned short* __restrict__ WkT,
                                                    float* __restrict__ numer,
                                                    float* __restrict__ denom,
                                                    int B) {
    __shared__ float fu[2][DIM];
    const int blk = blockIdx.x, t = threadIdx.x;
    const int qblocks = (B + 1) >> 1;
    if (blk < qblocks) {
        const int half = t >> 7, d = t & 127;
        const int b = blk * 2 + half;
        if (b < B) fu[half][d] = feat_u[b * DIM + d];
        __syncthreads();
        if (b < B) {
            float acc = b_user[d];
#pragma unroll 8
            for (int k = 0; k < DIM; ++k) acc += fu[half][k] * W_user[k * DIM + d];
            qry[b * DIM + d] = acc;
        }
    } else if (blk < qblocks + 64) {
        const int tid = (blk - qblocks) * 256 + t;
        const int k = tid >> 7, d = tid & 127;
        WkT[d * BSTRIDE + k] = f2bf(W_key[k * DIM + d]);
    } else {
        const int i = (blk - qblocks - 64) * 256 + t;
        if (i < B * DIM) numer[i] = 0.f;
        if (i < B) denom[i] = 0.f;
    }
}

// ---------------- K1 (fused, software-pipelined): per node ex = exp(sigmoid(qry+key)@W_e),
// accumulate numer[seg] += ex*feat_i, denom[seg] += ex (per-wave run, atomic flush on seg change).
// block = 256 threads (4 waves). Each wave: 8 strips of 16 nodes; strip s+1's A-loads are
// issued during strip s's body so the body hides global-load latency.
// NOTE: no occupancy bound — (256,3) forced VGPR 164->84 with ~300 B/thread scratch spill
// (WRITE_SIZE 8->153 MB, FETCH 254->925 MB). Plain bound allocates ~regs needed, no spill. ----------------
__global__ __launch_bounds__(256) void fused_kernel(const float* __restrict__ feat_i,
                                                    const int* __restrict__ seg,
                                                    const unsigned short* __restrict__ WkT,
                                                    const float* __restrict__ qry,
                                                    const float* __restrict__ W_e,
                                                    float* __restrict__ numer,
                                                    float* __restrict__ denom,
                                                    int N) {
    __shared__ __align__(16) unsigned short Blds[DIM * BSTRIDE];  // 34816 B
    __shared__ float We[DIM];
    int t = threadIdx.x;

    // stage WkT -> LDS as float4 chunks (34816 B = 2176 x 16 B)
    {
        const float4* src = (const float4*)WkT;
        float4* dst = (float4*)Blds;
        for (int i = t; i < (DIM * BSTRIDE) / 8; i += 256) dst[i] = src[i];
    }
    if (t < DIM) We[t] = W_e[t];
    __syncthreads();

    const int wave = t >> 6, lane = t & 63;
    const int m = lane & 15, quad = lane >> 4;
    const int base = blockIdx.x * 512 + wave * 128;
    const float2* f2 = (const float2*)feat_i;

    // strip-invariant W_e fragment (col = c*16+m) in registers
    float we[8];
#pragma unroll
    for (int c = 0; c < 8; ++c) we[c] = We[c * 16 + m];

    // phase-2 running state (lane owns output columns 2*lane, 2*lane+1)
    float2 wacc; wacc.x = 0.f; wacc.y = 0.f;
    float dsum = 0.f;
    int cur_sg = -1;

#define FLUSH()                                                            \
    do {                                                                   \
        atomicAdd(&numer[cur_sg * DIM + 2 * lane], wacc.x);                \
        atomicAdd(&numer[cur_sg * DIM + 2 * lane + 1], wacc.y);            \
        if (lane == 0) atomicAdd(&denom[cur_sg], dsum);                    \
        wacc.x = 0.f; wacc.y = 0.f; dsum = 0.f;                            \
    } while (0)

    // ---- prefetch buffer: lane's A-row slice. Address clamped for invalid rows; garbage
    // values only land in invalid C rows whose ev is never consumed (no masking needed). ----
    float4 pf[8];
    {
        const int n_a = base + m;
        const float* arow = feat_i + (size_t)(n_a < N ? n_a : 0) * DIM + quad * 8;
#pragma unroll
        for (int kc = 0; kc < 4; ++kc) {
            pf[2 * kc]     = *(const float4*)(arow + kc * 32);
            pf[2 * kc + 1] = *(const float4*)(arow + kc * 32 + 4);
        }
    }

#pragma unroll
    for (int s = 0; s < 8; ++s) {
        const int strip = base + s * 16;

        // ---- convert prefetched fp32 -> bf16 A fragments (frees pf for next issue) ----
        v8s a[4];
#pragma unroll
        for (int kc = 0; kc < 4; ++kc) {
            v8s af;
            af[0] = (short)f2bf(pf[2 * kc].x);
            af[1] = (short)f2bf(pf[2 * kc].y);
            af[2] = (short)f2bf(pf[2 * kc].z);
            af[3] = (short)f2bf(pf[2 * kc].w);
            af[4] = (short)f2bf(pf[2 * kc + 1].x);
            af[5] = (short)f2bf(pf[2 * kc + 1].y);
            af[6] = (short)f2bf(pf[2 * kc + 1].z);
            af[7] = (short)f2bf(pf[2 * kc + 1].w);
            a[kc] = af;
        }

        // ---- issue next strip's A-loads (in flight across this strip's body) ----
        if (s < 7) {
            const int n_n = base + (s + 1) * 16 + m;
            const float* arow = feat_i + (size_t)(n_n < N ? n_n : 0) * DIM + quad * 8;
#pragma unroll
            for (int kc = 0; kc < 4; ++kc) {
                pf[2 * kc]     = *(const float4*)(arow + kc * 32);
                pf[2 * kc + 1] = *(const float4*)(arow + kc * 32 + 4);
            }
        }

        // ---- MFMA: 8 col-tiles x 4 K-chunks ----
        v4f acc[8];
#pragma unroll
        for (int c = 0; c < 8; ++c) acc[c] = (v4f){0.f, 0.f, 0.f, 0.f};
#pragma unroll
        for (int c = 0; c < 8; ++c) {
            const unsigned short* brow = Blds + (c * 16 + m) * BSTRIDE + quad * 8;
#pragma unroll
            for (int kc = 0; kc < 4; ++kc) {
                v8s b = *(const v8s*)(brow + kc * 32);
                acc[c] = __builtin_amdgcn_mfma_f32_16x16x32_bf16(a[kc], b, acc[c], 0, 0, 0);
            }
        }

        // ---- epilogue: C row = quad*4 + r, col = c*16 + m ----
        float ev[4];
        int sgv[4];
#pragma unroll
        for (int r = 0; r < 4; ++r) {
            const int node = strip + quad * 4 + r;
            sgv[r] = (node < N) ? seg[node] : 0;
        }
        const int sgf = __shfl(sgv[0], 0);    // seg of first node in strip
        const int sgl = __shfl(sgv[3], 48);   // seg of last node in strip
        const bool uni = (sgf == sgl) && (strip + 15 < N);

        if (uni) {
            // strip-uniform segment: hoist qry gather (8 L2 loads instead of 32)
            float q[8];
#pragma unroll
            for (int c = 0; c < 8; ++c) q[c] = qry[sgf * DIM + c * 16 + m];
#pragma unroll
            for (int r = 0; r < 4; ++r) {
                float partial = 0.f;
#pragma unroll
                for (int c = 0; c < 8; ++c) {
                    const float x = acc[c][r] + q[c];
                    partial += __builtin_amdgcn_rcpf(1.0f + __expf(-x)) * we[c];
                }
                partial += __shfl_xor(partial, 1);
                partial += __shfl_xor(partial, 2);
                partial += __shfl_xor(partial, 4);
                partial += __shfl_xor(partial, 8);
                ev[r] = __expf(partial);
            }
        } else {
#pragma unroll
            for (int r = 0; r < 4; ++r) {
                const float* qrow = qry + sgv[r] * DIM;
                float partial = 0.f;
#pragma unroll
                for (int c = 0; c < 8; ++c) {
                    const float x = acc[c][r] + qrow[c * 16 + m];
                    partial += __builtin_amdgcn_rcpf(1.0f + __expf(-x)) * we[c];
                }
                partial += __shfl_xor(partial, 1);
                partial += __shfl_xor(partial, 2);
                partial += __shfl_xor(partial, 4);
                partial += __shfl_xor(partial, 8);
                ev[r] = __expf(partial);
            }
        }

        // ---- phase 2: ex-weighted accumulation over this strip's 16 nodes (L2-hot re-read) ----
        if (strip < N) {
            if (uni) {
                if (sgf != cur_sg) {
                    if (cur_sg >= 0) FLUSH();
                    cur_sg = sgf;
                }
#pragma unroll
                for (int i = 0; i < 16; ++i) {
                    const float w = __shfl(ev[i & 3], (i >> 2) * 16);
                    const float2 v = f2[(size_t)(strip + i) * 64 + lane];
                    wacc.x += w * v.x;
                    wacc.y += w * v.y;
                    dsum += w;
                }
            } else {
                // slow path: segment boundary (or N tail) inside the strip
#pragma unroll
                for (int i = 0; i < 16; ++i) {
                    const int n = strip + i;
                    if (n < N) {
                        const int sg = __shfl(sgv[i & 3], (i >> 2) * 16);
                        if (sg != cur_sg) {
                            if (cur_sg >= 0) FLUSH();
                            cur_sg = sg;
                        }
                        const float w = __shfl(ev[i & 3], (i >> 2) * 16);
                        const float2 v = f2[(size_t)n * 64 + lane];
                        wacc.x += w * v.x;
                        wacc.y += w * v.y;
                        dsum += w;
                    }
                }
            }
        }
    }

    if (cur_sg >= 0) FLUSH();
#undef FLUSH
}

// ---------------- K2: out[b][d] = numer[b][d] / denom[b] ----------------
__global__ void fin_kernel(const float* __restrict__ numer,
                           const float* __restrict__ denom,
                           float* __restrict__ out, int total) {
    int i = blockIdx.x * blockDim.x + threadIdx.x;
    if (i < total) {
        const float d = denom[i >> 7];
        out[i] = (d > 0.f) ? numer[i] / d : 0.f;
    }
}

extern "C" void kernel_launch(void* const* d_in, const int* in_sizes, int n_in,
                              void* d_out, int out_size, void* d_ws, size_t ws_size,
                              hipStream_t stream) {
    const float* feat_i = (const float*)d_in[0];
    const float* feat_u = (const float*)d_in[1];
    const int*   seg    = (const int*)d_in[2];
    const float* W_key  = (const float*)d_in[3];
    const float* W_user = (const float*)d_in[4];
    const float* b_user = (const float*)d_in[5];
    const float* W_e    = (const float*)d_in[6];
    float* out = (float*)d_out;

    const int N = in_sizes[2];
    const int B = in_sizes[1] / DIM;

    // workspace layout
    char* ws = (char*)d_ws;
    float*          qry   = (float*)ws;                                  // B*128*4   = 131072 B
    unsigned short* WkT   = (unsigned short*)(ws + 131072);              // 128*136*2 = 34816 B
    float*          numer = (float*)(ws + 131072 + 34816);               // B*128*4   = 131072 B
    float*          denom = (float*)(ws + 131072 + 34816 + 131072);     // B*4

    const int qblocks = (B + 1) >> 1;
    const int zblocks = (B * DIM + 255) / 256 + 1;
    setup_kernel<<<qblocks + 64 + zblocks, 256, 0, stream>>>(feat_u, W_user, b_user, W_key,
                                                             qry, WkT, numer, denom, B);

    const int nblk = (N + 511) / 512;
    fused_kernel<<<nblk, 256, 0, stream>>>(feat_i, seg, WkT, qry, W_e, numer, denom, N);

    fin_kernel<<<(B * DIM + 255) / 256, 256, 0, stream>>>(numer, denom, out, B * DIM);
}